// Round 1
// baseline (761.123 us; speedup 1.0000x reference)
//
#include <hip/hip_runtime.h>
#include <hip/hip_bf16.h>

#define NB 4
#define NS 8
#define NC 256
#define NHW 4096
#define NA 256
#define PT 8
#define NTH 512

typedef __hip_bfloat16 bf16;

__global__ __launch_bounds__(NTH, 1)
void fused_sa_kernel(const float* __restrict__ x,
                     const float* __restrict__ wq, const float* __restrict__ bq,
                     const float* __restrict__ wk, const float* __restrict__ bk,
                     const float* __restrict__ wv, const float* __restrict__ bv,
                     float* __restrict__ out)
{
    // LDS: 64K + 16.6K + 36.9K + 36.9K + 2K = 157.95 KB (<160K, 1 WG/CU)
    __shared__ float Xs[NC][PT][NS];      // [c][p][s']  fp32
    __shared__ float Wt[16][260];         // [c_local][a'] padded row (2-way-free)
    __shared__ bf16  Qs[NS][NA][PT + 1];  // [s'][a'][p] pad->9 ; V aliases this
    __shared__ bf16  Ks[NS][NA][PT + 1];
    __shared__ float Ps[PT][NS][NS];      // softmax probs [p][s][t]

    const int tid = threadIdx.x;
    // XCD-chunked swizzle: consecutive logical p-tiles land on the same XCD
    const int wg  = (int)(blockIdx.x & 7) * 256 + (int)(blockIdx.x >> 3);
    const int b   = wg >> 9;            // 512 tiles per batch (4096/8)
    const int p0  = (wg & 511) * PT;

    // ---- stage X: Xs[c][p][s'] = x[b, s', c, p0+p] ----
    // read pattern p-fastest (32B segments); write pattern is 2-way-free
#pragma unroll
    for (int i = 0; i < 32; ++i) {
        const int idx = i * NTH + tid;
        const int p  = idx & 7;
        const int sp = (idx >> 3) & 7;
        const int c  = idx >> 6;
        Xs[c][p][sp] = x[(size_t)((b * NS + sp) * NC + c) * NHW + p0 + p];
    }

    const int shalf = tid >> 8;         // 0..1   (s' half)
    const int agrp  = (tid >> 3) & 31;  // 0..31  (8 a' each)
    const int p     = tid & 7;

    for (int pr = 0; pr < 3; ++pr) {
        if (pr == 2) {
            // ======== scores + softmax (Q,K ready), before V overwrites Qs ====
            __syncthreads();
            const int s  = tid >> 6;          // wave index = s
            const int t  = (tid >> 3) & 7;
            const int pp = tid & 7;
            float sc = 0.f;
#pragma unroll
            for (int a = 0; a < NA; ++a) {
                const float qa = (float)Qs[a & 7][(s << 5) + (a >> 3)][pp];
                const float ka = (float)Ks[a >> 5][((a & 31) << 3) + t][pp];
                sc = fmaf(qa, ka, sc);
            }
            sc *= 0.0625f;                    // 1/sqrt(A)
            float m = sc;
            m = fmaxf(m, __shfl_xor(m, 8));
            m = fmaxf(m, __shfl_xor(m, 16));
            m = fmaxf(m, __shfl_xor(m, 32));
            const float e = __expf(sc - m);
            float sum = e;
            sum += __shfl_xor(sum, 8);
            sum += __shfl_xor(sum, 16);
            sum += __shfl_xor(sum, 32);
            Ps[pp][s][t] = e / sum;
            // projection's first barrier below makes Ps visible / Qs reusable
        }

        const float* const W  = (pr == 0) ? wq : ((pr == 1) ? wk : wv);
        const float* const Bb = (pr == 0) ? bq : ((pr == 1) ? bk : bv);

        float acc[4][8];
#pragma unroll
        for (int j = 0; j < 4; ++j)
#pragma unroll
            for (int u = 0; u < 8; ++u) acc[j][u] = 0.f;

        // prefetch weight k-tile 0 into regs
        float wreg[8];
#pragma unroll
        for (int i = 0; i < 8; ++i) {
            const int idx = i * NTH + tid;
            wreg[i] = W[(idx >> 4) * NC + (idx & 15)];
        }
        __syncthreads();   // all previous readers of Wt/Qs are done
#pragma unroll
        for (int i = 0; i < 8; ++i) {
            const int idx = i * NTH + tid;
            Wt[idx & 15][idx >> 4] = wreg[i];
        }
        __syncthreads();

        for (int kt = 0; kt < 16; ++kt) {
            if (kt < 15) {  // prefetch next tile; latency hides under compute
#pragma unroll
                for (int i = 0; i < 8; ++i) {
                    const int idx = i * NTH + tid;
                    wreg[i] = W[(idx >> 4) * NC + (kt + 1) * 16 + (idx & 15)];
                }
            }
#pragma unroll
            for (int cl = 0; cl < 16; ++cl) {
                const int c = kt * 16 + cl;
                const float4 w0 = *(const float4*)&Wt[cl][agrp * 8];
                const float4 w1 = *(const float4*)&Wt[cl][agrp * 8 + 4];
                const float4 xt = *(const float4*)&Xs[c][p][shalf * 4];
                const float xv[4] = { xt.x, xt.y, xt.z, xt.w };
#pragma unroll
                for (int j = 0; j < 4; ++j) {
                    acc[j][0] = fmaf(xv[j], w0.x, acc[j][0]);
                    acc[j][1] = fmaf(xv[j], w0.y, acc[j][1]);
                    acc[j][2] = fmaf(xv[j], w0.z, acc[j][2]);
                    acc[j][3] = fmaf(xv[j], w0.w, acc[j][3]);
                    acc[j][4] = fmaf(xv[j], w1.x, acc[j][4]);
                    acc[j][5] = fmaf(xv[j], w1.y, acc[j][5]);
                    acc[j][6] = fmaf(xv[j], w1.z, acc[j][6]);
                    acc[j][7] = fmaf(xv[j], w1.w, acc[j][7]);
                }
            }
            if (kt < 15) {
                __syncthreads();
#pragma unroll
                for (int i = 0; i < 8; ++i) {
                    const int idx = i * NTH + tid;
                    Wt[idx & 15][idx >> 4] = wreg[i];
                }
                __syncthreads();
            }
        }

        // store projection to LDS (bf16) with bias
        float bias[8];
#pragma unroll
        for (int u = 0; u < 8; ++u) bias[u] = Bb[agrp * 8 + u];
        bf16 (* const dst)[NA][PT + 1] = (pr == 1) ? Ks : Qs;  // V aliases Qs
#pragma unroll
        for (int j = 0; j < 4; ++j) {
            const int sp = shalf * 4 + j;
#pragma unroll
            for (int u = 0; u < 8; ++u) {
                dst[sp][agrp * 8 + u][p] = (bf16)(acc[j][u] + bias[u]);
            }
        }
    }

    __syncthreads();

    // ======== attended = P @ V, write out ========
    {
        const int g  = tid >> 3;    // 0..63, 4 a-values each
        const int pp = tid & 7;
        float v8[4][8];
#pragma unroll
        for (int aj = 0; aj < 4; ++aj) {
            const int a = (g << 2) + aj;
#pragma unroll
            for (int t = 0; t < 8; ++t)
                v8[aj][t] = (float)Qs[a & 7][(t << 5) + (a >> 3)][pp]; // V
        }
#pragma unroll
        for (int s = 0; s < 8; ++s) {
            float pr8[8];
#pragma unroll
            for (int t = 0; t < 8; ++t) pr8[t] = Ps[pp][s][t];
#pragma unroll
            for (int aj = 0; aj < 4; ++aj) {
                const int a = (g << 2) + aj;
                float av = 0.f;
#pragma unroll
                for (int t = 0; t < 8; ++t) av = fmaf(pr8[t], v8[aj][t], av);
                const int s2 = a & 7;
                const int a2 = (s << 5) + (a >> 3);
                out[(size_t)((b * NS + s2) * NA + a2) * NHW + p0 + pp] = av;
            }
        }
    }
}

extern "C" void kernel_launch(void* const* d_in, const int* in_sizes, int n_in,
                              void* d_out, int out_size, void* d_ws, size_t ws_size,
                              hipStream_t stream) {
    (void)in_sizes; (void)n_in; (void)d_ws; (void)ws_size; (void)out_size;
    const float* x  = (const float*)d_in[0];
    const float* wq = (const float*)d_in[1];
    const float* bq = (const float*)d_in[2];
    const float* wk = (const float*)d_in[3];
    const float* bk = (const float*)d_in[4];
    const float* wv = (const float*)d_in[5];
    const float* bv = (const float*)d_in[6];
    float* out = (float*)d_out;
    dim3 grid(2048), block(NTH);
    hipLaunchKernelGGL(fused_sa_kernel, grid, block, 0, stream,
                       x, wq, bq, wk, bk, wv, bv, out);
}

// Round 2
// 266.453 us; speedup vs baseline: 2.8565x; 2.8565x over previous
//
#include <hip/hip_runtime.h>
#include <hip/hip_bf16.h>

typedef __hip_bfloat16 bf16;
typedef __attribute__((ext_vector_type(8))) short short8;
typedef __attribute__((ext_vector_type(4))) float f32x4;

#define MFMA16(A, B, C) __builtin_amdgcn_mfma_f32_16x16x32_bf16((A), (B), (C), 0, 0, 0)

// ---------------- prep: W fp32 -> frag-major bf16 in ws ----------------
// ws layout: wsW[((proj*16 + mt)*8 + kk)*64 + lane][8]  (bf16)
// element = W[mt*16 + (lane&15)][kk*32 + (lane>>4)*8 + j]
__global__ __launch_bounds__(256) void prep_w(const float* __restrict__ wq,
                                              const float* __restrict__ wk,
                                              const float* __restrict__ wv,
                                              bf16* __restrict__ wsW)
{
    const int t = (int)blockIdx.x * 256 + (int)threadIdx.x;   // 0..24575
    const int lane = t & 63, kk = (t >> 6) & 7, mt = (t >> 9) & 15, proj = t >> 13;
    const float* W = (proj == 0) ? wq : ((proj == 1) ? wk : wv);
    const int row = mt * 16 + (lane & 15);
    const int col = kk * 32 + (lane >> 4) * 8;
    bf16* dst = wsW + (size_t)t * 8;
#pragma unroll
    for (int j = 0; j < 8; ++j) dst[j] = __float2bfloat16(W[row * 256 + col + j]);
}

// ---------------- fused main kernel ----------------
__device__ __forceinline__ void proj_mfma(const short8 (&wf)[2][8], f32x4 (&acc)[2][4],
                                          const bf16 (*Xp)[264], int c15, int h)
{
#pragma unroll
    for (int nt = 0; nt < 4; ++nt)
#pragma unroll
        for (int kk = 0; kk < 8; ++kk) {
            const short8 bx = *(const short8*)&Xp[nt * 16 + c15][kk * 32 + h * 8];
            acc[0][nt] = MFMA16(wf[0][kk], bx, acc[0][nt]);
            acc[1][nt] = MFMA16(wf[1][kk], bx, acc[1][nt]);
        }
}

__global__ __launch_bounds__(512, 2)
void fused_sa(const float* __restrict__ x,
              const float* __restrict__ bq, const float* __restrict__ bk,
              const float* __restrict__ bv,
              const bf16* __restrict__ wsW,
              float* __restrict__ out)
{
    __shared__ bf16 Xs[64][264];        // [col = s'*8+p][c]            33.8 KB
    __shared__ bf16 QL[8][9][264];      // [p][s_att][a_att]            38.0 KB
    __shared__ bf16 KL[8][9][264];      // [p][t_att][a_att]            38.0 KB
    __shared__ bf16 PL[8][8][8];        // [p][s][t] softmax probs       1.0 KB
    bf16 (* const VL2)[257][8] = (bf16 (*)[257][8])&QL[0][0][0];  // [p][a_att][t] aliases QL

    const int tid = (int)threadIdx.x;
    const int l = tid & 63, w = tid >> 6;       // wave w = 0..7
    const int h = l >> 4, c15 = l & 15;

    // XCD-chunked swizzle (2048 % 8 == 0, bijective)
    const int wg = (int)(blockIdx.x & 7) * 256 + (int)(blockIdx.x >> 3);
    const int b  = wg >> 9;
    const int p0 = (wg & 511) * 8;

    const short8* wsv = (const short8*)wsW;

    short8 wfA[2][8], wfB[2][8];
    // Q weight fragments (issue before staging)
#pragma unroll
    for (int mi = 0; mi < 2; ++mi) {
        const int mt = w + mi * 8;
#pragma unroll
        for (int kk = 0; kk < 8; ++kk)
            wfA[mi][kk] = wsv[((0 * 16 + mt) * 8 + kk) * 64 + l];
    }

    // ---- stage X -> Xs bf16 ----
    {
        const int p2 = (l & 3) * 2, chi = l >> 2;
#pragma unroll
        for (int i = 0; i < 16; ++i) {
            const int c = i * 16 + chi;
            const float2 v = *(const float2*)&x[((size_t)((b * 8 + w) * 256 + c)) * 4096 + p0 + p2];
            Xs[w * 8 + p2][c]     = __float2bfloat16(v.x);
            Xs[w * 8 + p2 + 1][c] = __float2bfloat16(v.y);
        }
    }
    // K weight fragments (issue before barrier; latency hides)
#pragma unroll
    for (int mi = 0; mi < 2; ++mi) {
        const int mt = w + mi * 8;
#pragma unroll
        for (int kk = 0; kk < 8; ++kk)
            wfB[mi][kk] = wsv[((1 * 16 + mt) * 8 + kk) * 64 + l];
    }
    __syncthreads();   // #1 Xs ready

    const int p = c15 & 7;                     // pixel (local) of this lane's col
    // ---- Q projection ----
    {
        f32x4 acc[2][4] = {};
        proj_mfma(wfA, acc, Xs, c15, h);
#pragma unroll
        for (int mi = 0; mi < 2; ++mi) {
            const int mt = w + mi * 8;
            const float4 bb = *(const float4*)&bq[mt * 16 + 4 * h];
            const float bbv[4] = {bb.x, bb.y, bb.z, bb.w};
#pragma unroll
            for (int nt = 0; nt < 4; ++nt) {
                const int sp = 2 * nt + (c15 >> 3);
#pragma unroll
                for (int r = 0; r < 4; ++r) {
                    const int ap = mt * 16 + 4 * h + r;   // a' row
                    QL[p][ap >> 5][((ap & 31) << 3) | sp] =
                        __float2bfloat16(acc[mi][nt][r] + bbv[r]);
                }
            }
        }
    }
    // V weight fragments (reuse wfA regs; issue early)
#pragma unroll
    for (int mi = 0; mi < 2; ++mi) {
        const int mt = w + mi * 8;
#pragma unroll
        for (int kk = 0; kk < 8; ++kk)
            wfA[mi][kk] = wsv[((2 * 16 + mt) * 8 + kk) * 64 + l];
    }
    // ---- K projection ----
    {
        f32x4 acc[2][4] = {};
        proj_mfma(wfB, acc, Xs, c15, h);
#pragma unroll
        for (int mi = 0; mi < 2; ++mi) {
            const int mt = w + mi * 8;
            const float4 bb = *(const float4*)&bk[mt * 16 + 4 * h];
            const float bbv[4] = {bb.x, bb.y, bb.z, bb.w};
#pragma unroll
            for (int nt = 0; nt < 4; ++nt) {
                const int sp = 2 * nt + (c15 >> 3);
#pragma unroll
                for (int r = 0; r < 4; ++r) {
                    const int ap = mt * 16 + 4 * h + r;
                    KL[p][ap & 7][(sp << 5) | (ap >> 3)] =
                        __float2bfloat16(acc[mi][nt][r] + bbv[r]);
                }
            }
        }
    }
    __syncthreads();   // #2 QL, KL ready

    // ---- scores + softmax (waves 0-3; tile q pairs pixels 2q,2q+1) ----
    f32x4 vacc[2][4] = {};
    if (w < 4) {
        const int q = w;
        const int pxr = c15 >> 3, st = c15 & 7;
        f32x4 sacc = {0.f, 0.f, 0.f, 0.f};
#pragma unroll
        for (int kk = 0; kk < 8; ++kk) {
            const short8 qa = *(const short8*)&QL[2 * q + pxr][st][kk * 32 + h * 8];
            const short8 kb = *(const short8*)&KL[2 * q + pxr][st][kk * 32 + h * 8];
            sacc = MFMA16(qa, kb, sacc);
        }
        const bool valid = ((h >> 1) == pxr);
        const int px = 2 * q + (h >> 1);
#pragma unroll
        for (int r = 0; r < 4; ++r) {
            const float S = sacc[r] * 0.0625f;
            float m = S;
            m = fmaxf(m, __shfl_xor(m, 1));
            m = fmaxf(m, __shfl_xor(m, 2));
            m = fmaxf(m, __shfl_xor(m, 4));
            const float e = __expf(S - m);
            float sm = e;
            sm += __shfl_xor(sm, 1);
            sm += __shfl_xor(sm, 2);
            sm += __shfl_xor(sm, 4);
            if (valid) PL[px][4 * (h & 1) + r][st] = __float2bfloat16(e / sm);
        }
    }
    // ---- V projection MFMAs (all waves; epilogue deferred past barrier) ----
    proj_mfma(wfA, vacc, Xs, c15, h);
    __syncthreads();   // #3 scores' QL reads done; PL written

    // ---- V epilogue -> VL2 (aliases QL) ----
    {
#pragma unroll
        for (int mi = 0; mi < 2; ++mi) {
            const int mt = w + mi * 8;
            const float4 bb = *(const float4*)&bv[mt * 16 + 4 * h];
            const float bbv[4] = {bb.x, bb.y, bb.z, bb.w};
#pragma unroll
            for (int nt = 0; nt < 4; ++nt) {
                const int sp = 2 * nt + (c15 >> 3);
#pragma unroll
                for (int r = 0; r < 4; ++r) {
                    const int ap = mt * 16 + 4 * h + r;
                    VL2[p][((ap & 31) << 3) | sp][ap >> 5] =
                        __float2bfloat16(vacc[mi][nt][r] + bbv[r]);
                }
            }
        }
    }
    __syncthreads();   // #4 VL2, PL ready

    // ---- PV: attended = P @ V via block-diagonal A, write out ----
    const short8 zv = {0, 0, 0, 0, 0, 0, 0, 0};
#pragma unroll
    for (int g = 0; g < 2; ++g)
#pragma unroll
        for (int T = 0; T < 2; ++T) {
            short8 pa = *(const short8*)&PL[4 * g + 2 * T + (c15 >> 3)][c15 & 7][0];
            if (h != 2 * T + (c15 >> 3)) pa = zv;   // block-diagonal zero
#pragma unroll
            for (int ci = 0; ci < 2; ++ci) {
                const int ct = 2 * w + ci;
                const short8 vb = *(const short8*)&VL2[4 * g + h][16 * ct + c15][0];
                f32x4 pacc = {0.f, 0.f, 0.f, 0.f};
                pacc = MFMA16(pa, vb, pacc);
                const int a = 16 * ct + c15;
                const int pix = 4 * g + 2 * T + (h >> 1);
                const int s_base = 4 * (h & 1);
                float* op = &out[((size_t)((b * 8 + (a & 7)) * 256 + (a >> 3))) * 4096 + p0 + pix];
#pragma unroll
                for (int r = 0; r < 4; ++r) {
                    op[(size_t)((s_base + r) << 5) * 4096] = pacc[r];
                }
            }
        }
}

extern "C" void kernel_launch(void* const* d_in, const int* in_sizes, int n_in,
                              void* d_out, int out_size, void* d_ws, size_t ws_size,
                              hipStream_t stream) {
    (void)in_sizes; (void)n_in; (void)out_size; (void)ws_size;
    const float* x  = (const float*)d_in[0];
    const float* wq = (const float*)d_in[1];
    const float* bq = (const float*)d_in[2];
    const float* wk = (const float*)d_in[3];
    const float* bk = (const float*)d_in[4];
    const float* wv = (const float*)d_in[5];
    const float* bv = (const float*)d_in[6];
    float* out = (float*)d_out;
    bf16* wsW  = (bf16*)d_ws;   // needs 3*16*8*64*8*2 = 393,216 bytes

    hipLaunchKernelGGL(prep_w, dim3(96), dim3(256), 0, stream, wq, wk, wv, wsW);
    hipLaunchKernelGGL(fused_sa, dim3(2048), dim3(512), 0, stream,
                       x, bq, bk, bv, wsW, out);
}